// Round 1
// baseline (233.181 us; speedup 1.0000x reference)
//
#include <hip/hip_runtime.h>
#include <stdint.h>

#define M_TOK 512
#define N_OUT 11008
#define K_IN  4096
#define BM 128
#define BN 128
#define BK 64
#define NTILES (K_IN / BK)   // 64 k-steps

typedef __bf16 bf16x8 __attribute__((ext_vector_type(8)));
typedef float  f32x4  __attribute__((ext_vector_type(4)));

// ---- conversions -----------------------------------------------------------
__device__ __forceinline__ uint32_t bf_rne(float f) {
  uint32_t u = __float_as_uint(f);
  return (u + 0x7FFFu + ((u >> 16) & 1u)) >> 16;
}
__device__ __forceinline__ uint32_t pk_f(float a, float b) {
  return bf_rne(a) | (bf_rne(b) << 16);
}
__device__ __forceinline__ uint32_t pk_i(int a, int b) {
  // ints in [-127,127] are exactly representable in bf16 -> truncation is exact
  return (__float_as_uint((float)a) >> 16) | (__float_as_uint((float)b) & 0xFFFF0000u);
}

// ---- x f32 -> bf16 pre-pass (512*4096 = 2,097,152 elems; 8 per thread) -----
__global__ void xcvt_kernel(const float4* __restrict__ x, uint4* __restrict__ o) {
  int i = blockIdx.x * blockDim.x + threadIdx.x;
  float4 a = x[2 * i];
  float4 b = x[2 * i + 1];
  uint4 h;
  h.x = pk_f(a.x, a.y);
  h.y = pk_f(a.z, a.w);
  h.z = pk_f(b.x, b.y);
  h.w = pk_f(b.z, b.w);
  o[i] = h;
}

// ---- LDS helpers -----------------------------------------------------------
// Tile layout: [row][64 bf16] = 128B rows. 16B chunk c within row stored at
// chunk (c ^ (row&7))  -> XOR swizzle kills the 16/32-way read conflict (G4).

__device__ __forceinline__ void b_write(uint16_t* bs, const int4* w, int row, int half) {
#pragma unroll
  for (int c = 0; c < 4; ++c) {
    uint4 h;
    h.x = pk_i(w[2 * c].x, w[2 * c].y);
    h.y = pk_i(w[2 * c].z, w[2 * c].w);
    h.z = pk_i(w[2 * c + 1].x, w[2 * c + 1].y);
    h.w = pk_i(w[2 * c + 1].z, w[2 * c + 1].w);
    int ch = (half * 4 + c) ^ (row & 7);
    *(uint4*)&bs[row * 64 + ch * 8] = h;
  }
}

__device__ __forceinline__ void a_write_f32(uint16_t* as, const float4* v, int row, int half) {
#pragma unroll
  for (int c = 0; c < 4; ++c) {
    uint4 h;
    h.x = pk_f(v[2 * c].x, v[2 * c].y);
    h.y = pk_f(v[2 * c].z, v[2 * c].w);
    h.z = pk_f(v[2 * c + 1].x, v[2 * c + 1].y);
    h.w = pk_f(v[2 * c + 1].z, v[2 * c + 1].w);
    int ch = (half * 4 + c) ^ (row & 7);
    *(uint4*)&as[row * 64 + ch * 8] = h;
  }
}

// A tile via global_load_lds (LDS dest linear, swizzle applied on global src)
__device__ __forceinline__ void a_gload(const uint16_t* __restrict__ xb, int bm0, int kbase,
                                        uint16_t* as, int wid, int lane) {
#pragma unroll
  for (int it = 0; it < 4; ++it) {
    int s = wid * 4 + it;              // 16 segments of 1KB (8 rows each)
    int row = s * 8 + (lane >> 3);
    int gch = (lane & 7) ^ (row & 7);  // inverse-swizzled source chunk
    const uint16_t* g = xb + (size_t)(bm0 + row) * K_IN + kbase + gch * 8;
    __builtin_amdgcn_global_load_lds((const __attribute__((address_space(1))) void*)g,
                                     (__attribute__((address_space(3))) void*)&as[s * 512],
                                     16, 0, 0);
  }
}

// ---- GEMM ------------------------------------------------------------------
// 256 threads = 4 waves (2x2), each wave owns 64x64 = 4x4 frags of 16x16.
template <bool USE_WS>
__global__ __launch_bounds__(256)
void qgemm(const uint16_t* __restrict__ xb, const float* __restrict__ xf,
           const int* __restrict__ qw, const float* __restrict__ scale,
           const float* __restrict__ bias, float* __restrict__ out) {
  __shared__ uint16_t As[2][BM * BK];  // 16KB each
  __shared__ uint16_t Bs[2][BN * BK];  // 16KB each  (total 64KB)

  const int tid = threadIdx.x;
  const int lane = tid & 63;
  const int wid = tid >> 6;
  const int wm = wid >> 1, wn = wid & 1;

  const int bid = blockIdx.x;
  const int mt = bid & 3;   // M_TOK/BM == 4; consecutive bids share the W panel
  const int nt = bid >> 2;
  const int bm0 = mt * BM, bn0 = nt * BN;

  const int srow = tid >> 1;  // 0..127: staging row
  const int shalf = tid & 1;  // which 32-elem half of the 64-wide k window

  f32x4 acc[4][4] = {};

  int4 wreg[8];
  float4 av[8];

  // ---- prologue: stage k-tile 0 into buffer 0 ----
  {
    const int4* g = (const int4*)(qw + (size_t)(bn0 + srow) * K_IN + shalf * 32);
#pragma unroll
    for (int i = 0; i < 8; ++i) wreg[i] = g[i];
    if constexpr (USE_WS) {
      a_gload(xb, bm0, 0, As[0], wid, lane);
    } else {
      const float4* ga = (const float4*)(xf + (size_t)(bm0 + srow) * K_IN + shalf * 32);
#pragma unroll
      for (int i = 0; i < 8; ++i) av[i] = ga[i];
      a_write_f32(As[0], av, srow, shalf);
    }
    b_write(Bs[0], wreg, srow, shalf);
  }
  __syncthreads();

  // ---- main K loop ----
  for (int t = 0; t < NTILES; ++t) {
    const int cur = t & 1;
    const bool has_next = (t + 1 < NTILES);
    const int kn = (t + 1) * BK;

    if (has_next) {
      const int4* g = (const int4*)(qw + (size_t)(bn0 + srow) * K_IN + kn + shalf * 32);
#pragma unroll
      for (int i = 0; i < 8; ++i) wreg[i] = g[i];
      if constexpr (USE_WS) {
        a_gload(xb, bm0, kn, As[cur ^ 1], wid, lane);
      } else {
        const float4* ga = (const float4*)(xf + (size_t)(bm0 + srow) * K_IN + kn + shalf * 32);
#pragma unroll
        for (int i = 0; i < 8; ++i) av[i] = ga[i];
      }
    }

    // compute on buf[cur]
    const int kq = lane >> 4;
#pragma unroll
    for (int kk = 0; kk < 2; ++kk) {
      bf16x8 a[4], b[4];
#pragma unroll
      for (int mi = 0; mi < 4; ++mi) {
        int row = wm * 64 + mi * 16 + (lane & 15);
        int ch = (kk * 4 + kq) ^ (row & 7);
        a[mi] = *(const bf16x8*)&As[cur][row * 64 + ch * 8];
      }
#pragma unroll
      for (int ni = 0; ni < 4; ++ni) {
        int row = wn * 64 + ni * 16 + (lane & 15);
        int ch = (kk * 4 + kq) ^ (row & 7);
        b[ni] = *(const bf16x8*)&Bs[cur][row * 64 + ch * 8];
      }
#pragma unroll
      for (int mi = 0; mi < 4; ++mi)
#pragma unroll
        for (int ni = 0; ni < 4; ++ni)
          acc[mi][ni] = __builtin_amdgcn_mfma_f32_16x16x32_bf16(a[mi], b[ni], acc[mi][ni], 0, 0, 0);
    }

    if (has_next) {
      if constexpr (!USE_WS) a_write_f32(As[cur ^ 1], av, srow, shalf);
      b_write(Bs[cur ^ 1], wreg, srow, shalf);
    }
    __syncthreads();
  }

  // ---- epilogue: out = acc * scale[col] + bias[col] ----
  const int kq = lane >> 4;
#pragma unroll
  for (int ni = 0; ni < 4; ++ni) {
    int col = bn0 + wn * 64 + ni * 16 + (lane & 15);
    float sc = scale[col];
    float bi = bias[col];
#pragma unroll
    for (int mi = 0; mi < 4; ++mi) {
      int rowb = bm0 + wm * 64 + mi * 16 + kq * 4;
#pragma unroll
      for (int r = 0; r < 4; ++r) {
        out[(size_t)(rowb + r) * N_OUT + col] = acc[mi][ni][r] * sc + bi;
      }
    }
  }
}

// ---- launch ----------------------------------------------------------------
extern "C" void kernel_launch(void* const* d_in, const int* in_sizes, int n_in,
                              void* d_out, int out_size, void* d_ws, size_t ws_size,
                              hipStream_t stream) {
  const float* x = (const float*)d_in[0];
  const int* qw = (const int*)d_in[1];
  const float* scale = (const float*)d_in[2];
  const float* bias = (const float*)d_in[3];
  float* out = (float*)d_out;

  const dim3 grid((M_TOK / BM) * (N_OUT / BN));  // 4 * 86 = 344
  const dim3 block(256);
  const size_t xb_bytes = (size_t)M_TOK * K_IN * sizeof(uint16_t);  // 4 MB

  if (ws_size >= xb_bytes) {
    uint16_t* xb = (uint16_t*)d_ws;
    // 2,097,152 elems / (256 thr * 8 elems) = 1024 blocks
    xcvt_kernel<<<1024, 256, 0, stream>>>((const float4*)x, (uint4*)xb);
    qgemm<true><<<grid, block, 0, stream>>>(xb, x, qw, scale, bias, out);
  } else {
    qgemm<false><<<grid, block, 0, stream>>>(nullptr, x, qw, scale, bias, out);
  }
}

// Round 2
// 107.653 us; speedup vs baseline: 2.1660x; 2.1660x over previous
//
#include <hip/hip_runtime.h>
#include <stdint.h>

#define M_TOK 512
#define N_OUT 11008
#define K_IN  4096
#define BM 128
#define BN 128
#define BK 64
#define NTILES (K_IN / BK)   // 64 k-steps

typedef __bf16 bf16x8 __attribute__((ext_vector_type(8)));
typedef float  f32x4  __attribute__((ext_vector_type(4)));

// ---- conversions -----------------------------------------------------------
__device__ __forceinline__ uint32_t bf_rne(float f) {
  uint32_t u = __float_as_uint(f);
  return (u + 0x7FFFu + ((u >> 16) & 1u)) >> 16;
}
__device__ __forceinline__ uint32_t pk_f(float a, float b) {
  return bf_rne(a) | (bf_rne(b) << 16);
}
__device__ __forceinline__ uint32_t pk_i(int a, int b) {
  // ints in [-127,127] are exactly representable in bf16 -> truncation is exact
  return (__float_as_uint((float)a) >> 16) | (__float_as_uint((float)b) & 0xFFFF0000u);
}

// ---- x f32 -> bf16 pre-pass (512*4096 = 2,097,152 elems; 8 per thread) -----
__global__ void xcvt_kernel(const float4* __restrict__ x, uint4* __restrict__ o) {
  int i = blockIdx.x * blockDim.x + threadIdx.x;
  float4 a = x[2 * i];
  float4 b = x[2 * i + 1];
  uint4 h;
  h.x = pk_f(a.x, a.y);
  h.y = pk_f(a.z, a.w);
  h.z = pk_f(b.x, b.y);
  h.w = pk_f(b.z, b.w);
  o[i] = h;
}

// ---- LDS layout -------------------------------------------------------------
// Tile [row][64 bf16] = 128B rows, 8 chunks of 16B. Chunk c of row r stored at
// chunk (c ^ (r&7)) -> Latin-square XOR swizzle (G4). Same convention for A & B.

// A tile via global_load_lds (LDS dest linear, swizzle applied on global src)
__device__ __forceinline__ void a_gload(const uint16_t* __restrict__ xb, int bm0, int kbase,
                                        uint16_t* as, int wid, int lane) {
#pragma unroll
  for (int it = 0; it < 4; ++it) {
    int s = wid * 4 + it;              // 16 segments of 1KB (8 rows each)
    int row = s * 8 + (lane >> 3);
    int gch = (lane & 7) ^ (row & 7);  // inverse-swizzled source chunk
    const uint16_t* g = xb + (size_t)(bm0 + row) * K_IN + kbase + gch * 8;
    __builtin_amdgcn_global_load_lds((const __attribute__((address_space(1))) void*)g,
                                     (__attribute__((address_space(3))) void*)&as[s * 512],
                                     16, 0, 0);
  }
}

// B (W) staging: COALESCED. cid = tid + i*256 over i=0..3 covers 1024 chunks of
// 32B; row = cid>>3 (128 rows), seg = cid&7 (8 x 32B segments per 256B row
// window). A wave instruction covers 8 contiguous row-segments (fully packed
// 64B sectors) instead of 64 scattered ones.
__device__ __forceinline__ void b_load(const int* __restrict__ qw, int bn0, int kbase,
                                       int tid, int4* wr) {
#pragma unroll
  for (int i = 0; i < 4; ++i) {
    int cid = tid + i * 256;
    int row = cid >> 3;
    int seg = cid & 7;
    const int4* g = (const int4*)(qw + (size_t)(bn0 + row) * K_IN + kbase + seg * 8);
    wr[2 * i] = g[0];
    wr[2 * i + 1] = g[1];
  }
}

__device__ __forceinline__ void b_write(uint16_t* bs, const int4* wr, int tid) {
#pragma unroll
  for (int i = 0; i < 4; ++i) {
    int cid = tid + i * 256;
    int row = cid >> 3;
    int seg = cid & 7;
    uint4 h;
    h.x = pk_i(wr[2 * i].x, wr[2 * i].y);
    h.y = pk_i(wr[2 * i].z, wr[2 * i].w);
    h.z = pk_i(wr[2 * i + 1].x, wr[2 * i + 1].y);
    h.w = pk_i(wr[2 * i + 1].z, wr[2 * i + 1].w);
    int ch = seg ^ (row & 7);
    *(uint4*)&bs[row * 64 + ch * 8] = h;
  }
}

// A staging fallback (no workspace): f32 -> bf16 in-kernel, same coalesced shape
__device__ __forceinline__ void a_load_f32(const float* __restrict__ xf, int bm0, int kbase,
                                           int tid, float4* ar) {
#pragma unroll
  for (int i = 0; i < 4; ++i) {
    int cid = tid + i * 256;
    int row = cid >> 3;
    int seg = cid & 7;
    const float4* g = (const float4*)(xf + (size_t)(bm0 + row) * K_IN + kbase + seg * 8);
    ar[2 * i] = g[0];
    ar[2 * i + 1] = g[1];
  }
}

__device__ __forceinline__ void a_write_f32(uint16_t* as, const float4* ar, int tid) {
#pragma unroll
  for (int i = 0; i < 4; ++i) {
    int cid = tid + i * 256;
    int row = cid >> 3;
    int seg = cid & 7;
    uint4 h;
    h.x = pk_f(ar[2 * i].x, ar[2 * i].y);
    h.y = pk_f(ar[2 * i].z, ar[2 * i].w);
    h.z = pk_f(ar[2 * i + 1].x, ar[2 * i + 1].y);
    h.w = pk_f(ar[2 * i + 1].z, ar[2 * i + 1].w);
    int ch = seg ^ (row & 7);
    *(uint4*)&as[row * 64 + ch * 8] = h;
  }
}

// ---- GEMM ------------------------------------------------------------------
// 256 threads = 4 waves (2x2), each wave owns 64x64 = 4x4 frags of 16x16.
template <bool USE_WS>
__global__ __launch_bounds__(256)
void qgemm(const uint16_t* __restrict__ xb, const float* __restrict__ xf,
           const int* __restrict__ qw, const float* __restrict__ scale,
           const float* __restrict__ bias, float* __restrict__ out) {
  __shared__ uint16_t As[2][BM * BK];  // 16KB each
  __shared__ uint16_t Bs[2][BN * BK];  // 16KB each  (total 64KB -> 2 blocks/CU)

  const int tid = threadIdx.x;
  const int lane = tid & 63;
  const int wid = tid >> 6;
  const int wm = wid >> 1, wn = wid & 1;

  // XCD-aware mapping: dispatch round-robins bid%8 across XCDs. Give each XCD a
  // contiguous chunk of work so a W panel's 4 M-tiles share one XCD's L2.
  // grid = 344 = 8 * 43 exactly.
  const int xcd = blockIdx.x & 7;
  const int j = blockIdx.x >> 3;     // 0..42
  const int g = xcd * 43 + j;        // contiguous work per XCD
  const int nt = g >> 2;             // panel 0..85
  const int mt = g & 3;              // 4 M-tiles of the panel, adjacent on XCD
  const int bm0 = mt * BM, bn0 = nt * BN;

  f32x4 acc[4][4] = {};

  int4 wreg[8];
  float4 areg[8];

  // ---- prologue: stage k-tile 0 into buffer 0 ----
  {
    b_load(qw, bn0, 0, tid, wreg);
    if constexpr (USE_WS) {
      a_gload(xb, bm0, 0, As[0], wid, lane);
    } else {
      a_load_f32(xf, bm0, 0, tid, areg);
      a_write_f32(As[0], areg, tid);
    }
    b_write(Bs[0], wreg, tid);
  }
  __syncthreads();

  // ---- main K loop ----
  for (int t = 0; t < NTILES; ++t) {
    const int cur = t & 1;
    const bool has_next = (t + 1 < NTILES);
    const int kn = (t + 1) * BK;

    if (has_next) {
      b_load(qw, bn0, kn, tid, wreg);
      if constexpr (USE_WS) {
        a_gload(xb, bm0, kn, As[cur ^ 1], wid, lane);
      } else {
        a_load_f32(xf, bm0, kn, tid, areg);
      }
    }

    // compute on buf[cur]
    const int kq = lane >> 4;
#pragma unroll
    for (int kk = 0; kk < 2; ++kk) {
      bf16x8 a[4], b[4];
#pragma unroll
      for (int mi = 0; mi < 4; ++mi) {
        int row = wm * 64 + mi * 16 + (lane & 15);
        int ch = (kk * 4 + kq) ^ (row & 7);
        a[mi] = *(const bf16x8*)&As[cur][row * 64 + ch * 8];
      }
#pragma unroll
      for (int ni = 0; ni < 4; ++ni) {
        int row = wn * 64 + ni * 16 + (lane & 15);
        int ch = (kk * 4 + kq) ^ (row & 7);
        b[ni] = *(const bf16x8*)&Bs[cur][row * 64 + ch * 8];
      }
#pragma unroll
      for (int mi = 0; mi < 4; ++mi)
#pragma unroll
        for (int ni = 0; ni < 4; ++ni)
          acc[mi][ni] = __builtin_amdgcn_mfma_f32_16x16x32_bf16(a[mi], b[ni], acc[mi][ni], 0, 0, 0);
    }

    if (has_next) {
      if constexpr (!USE_WS) a_write_f32(As[cur ^ 1], areg, tid);
      b_write(Bs[cur ^ 1], wreg, tid);
    }
    __syncthreads();
  }

  // ---- epilogue: out = acc * scale[col] + bias[col] ----
  const int kq = lane >> 4;
#pragma unroll
  for (int ni = 0; ni < 4; ++ni) {
    int col = bn0 + wn * 64 + ni * 16 + (lane & 15);
    float sc = scale[col];
    float bi = bias[col];
#pragma unroll
    for (int mi = 0; mi < 4; ++mi) {
      int rowb = bm0 + wm * 64 + mi * 16 + kq * 4;
#pragma unroll
      for (int r = 0; r < 4; ++r) {
        out[(size_t)(rowb + r) * N_OUT + col] = acc[mi][ni][r] * sc + bi;
      }
    }
  }
}

// ---- launch ----------------------------------------------------------------
extern "C" void kernel_launch(void* const* d_in, const int* in_sizes, int n_in,
                              void* d_out, int out_size, void* d_ws, size_t ws_size,
                              hipStream_t stream) {
  const float* x = (const float*)d_in[0];
  const int* qw = (const int*)d_in[1];
  const float* scale = (const float*)d_in[2];
  const float* bias = (const float*)d_in[3];
  float* out = (float*)d_out;

  const dim3 grid((M_TOK / BM) * (N_OUT / BN));  // 4 * 86 = 344
  const dim3 block(256);
  const size_t xb_bytes = (size_t)M_TOK * K_IN * sizeof(uint16_t);  // 4 MB

  if (ws_size >= xb_bytes) {
    uint16_t* xb = (uint16_t*)d_ws;
    xcvt_kernel<<<1024, 256, 0, stream>>>((const float4*)x, (uint4*)xb);
    qgemm<true><<<grid, block, 0, stream>>>(xb, x, qw, scale, bias, out);
  } else {
    qgemm<false><<<grid, block, 0, stream>>>(nullptr, x, qw, scale, bias, out);
  }
}